// Round 3
// baseline (358.338 us; speedup 1.0000x reference)
//
#include <hip/hip_runtime.h>
#include <hip/hip_bf16.h>
#include <stdint.h>

#define NN 50000
#define NE 800000
#define KDIM 256
#define DDIM 64
#define ALPHA 0.2f
#define EPSV 9e-15f

// workspace layout (float offsets)
#define OFF_ACC    0            // 3,200,000 floats (zeroed)
#define OFF_ROWSUM 3200000      // 50,000 floats (zeroed)
#define OFF_MAX    3250000      // scratch for global max (zeroed)
#define OFF_H      3250016      // 3,200,000 floats
#define OFF_S      6450016      // 50,000 floats
#define OFF_T      6500016      // 50,000 floats
// total = 6,550,016 floats = 26.2 MB

typedef __bf16 bf16x8 __attribute__((ext_vector_type(8)));
typedef float f32x4 __attribute__((ext_vector_type(4)));

__device__ __forceinline__ ushort f2bf(float f) {
    uint32_t u = __float_as_uint(f);
    uint32_t r = (u + 0x7fffu + ((u >> 16) & 1u)) >> 16;  // RNE
    return (ushort)r;
}

// ---------------- K1: h = x @ W  (f32 in, cast to bf16, fp32 out) ----------------
// 16x16x32 bf16 MFMA. Each wave holds all of W as 4(n-tiles) x 8(k-steps)
// B-fragments in registers (converted once), grid-strides over 3125 M-tiles.
__global__ __launch_bounds__(256) void k_gemm(const float* __restrict__ X,
                                              const float* __restrict__ W,
                                              float* __restrict__ H) {
    const int lane = threadIdx.x & 63;
    const int wave = blockIdx.x * 4 + (threadIdx.x >> 6);
    const int nwaves = gridDim.x * 4;
    const int quad = lane >> 4;   // 0..3
    const int nn = lane & 15;     // 0..15

    // B fragments: B[k][n], k = s*32 + quad*8 + j, n = t*16 + nn
    bf16x8 bfrag[4][8];
#pragma unroll
    for (int t = 0; t < 4; ++t) {
#pragma unroll
        for (int s = 0; s < 8; ++s) {
            union { ushort u[8]; bf16x8 v; } bb;
#pragma unroll
            for (int j = 0; j < 8; ++j) {
                int k = s * 32 + quad * 8 + j;
                bb.u[j] = f2bf(W[k * DDIM + t * 16 + nn]);
            }
            bfrag[t][s] = bb.v;
        }
    }

    const int MT = NN / 16;  // 3125 exactly
    for (int mt = wave; mt < MT; mt += nwaves) {
        const int row0 = mt * 16;
        // A fragments: A[m][k], m = nn, k = s*32 + quad*8 + j
        const float* xr = X + (size_t)(row0 + nn) * KDIM + quad * 8;
        bf16x8 afrag[8];
#pragma unroll
        for (int s = 0; s < 8; ++s) {
            float4 lo = *reinterpret_cast<const float4*>(xr + s * 32);
            float4 hi = *reinterpret_cast<const float4*>(xr + s * 32 + 4);
            union { ushort u[8]; bf16x8 v; } aa;
            aa.u[0] = f2bf(lo.x); aa.u[1] = f2bf(lo.y);
            aa.u[2] = f2bf(lo.z); aa.u[3] = f2bf(lo.w);
            aa.u[4] = f2bf(hi.x); aa.u[5] = f2bf(hi.y);
            aa.u[6] = f2bf(hi.z); aa.u[7] = f2bf(hi.w);
            afrag[s] = aa.v;
        }

        f32x4 acc[4];
#pragma unroll
        for (int t = 0; t < 4; ++t) acc[t] = {0.f, 0.f, 0.f, 0.f};

#pragma unroll
        for (int s = 0; s < 8; ++s)
#pragma unroll
            for (int t = 0; t < 4; ++t)
                acc[t] = __builtin_amdgcn_mfma_f32_16x16x32_bf16(
                    afrag[s], bfrag[t][s], acc[t], 0, 0, 0);

        // D: row = quad*4 + r, col = t*16 + nn
#pragma unroll
        for (int t = 0; t < 4; ++t)
#pragma unroll
            for (int r = 0; r < 4; ++r)
                H[(size_t)(row0 + quad * 4 + r) * DDIM + t * 16 + nn] = acc[t][r];
    }
}

// ---------------- K2: s = h @ a_src, t = h @ a_dst ----------------
__global__ __launch_bounds__(256) void k_st(const float* __restrict__ H,
                                            const float* __restrict__ attn,
                                            float* __restrict__ S,
                                            float* __restrict__ T) {
    __shared__ float a_s[DDIM];
    __shared__ float a_d[DDIM];
    if (threadIdx.x < 2 * DDIM) {
        float v = attn[threadIdx.x];
        if (threadIdx.x < DDIM) a_s[threadIdx.x] = v;
        else a_d[threadIdx.x - DDIM] = v;
    }
    __syncthreads();
    for (int i = blockIdx.x * 256 + threadIdx.x; i < NN; i += gridDim.x * 256) {
        const float4* hr = (const float4*)(H + (size_t)i * DDIM);
        float s = 0.f, t = 0.f;
#pragma unroll
        for (int c = 0; c < 16; ++c) {
            float4 h4 = hr[c];
            s += h4.x * a_s[c * 4 + 0] + h4.y * a_s[c * 4 + 1] +
                 h4.z * a_s[c * 4 + 2] + h4.w * a_s[c * 4 + 3];
            t += h4.x * a_d[c * 4 + 0] + h4.y * a_d[c * 4 + 1] +
                 h4.z * a_d[c * 4 + 2] + h4.w * a_d[c * 4 + 3];
        }
        S[i] = s;
        T[i] = t;
    }
}

// ---------------- K3: global max of leaky-relu logits ----------------
__global__ __launch_bounds__(256) void k_max(const int* __restrict__ edge,
                                             const float* __restrict__ S,
                                             const float* __restrict__ T,
                                             float* __restrict__ MX) {
    float m = 0.0f;  // true max is certainly > 0; int-compare valid for >= 0
    for (int e = blockIdx.x * 256 + threadIdx.x; e < NE; e += gridDim.x * 256) {
        int src = edge[e];
        int dst = edge[NE + e];
        float v = S[src] + T[dst];
        float a = v >= 0.f ? v : ALPHA * v;
        m = fmaxf(m, a);
    }
#pragma unroll
    for (int off = 32; off > 0; off >>= 1)
        m = fmaxf(m, __shfl_down(m, off, 64));
    if ((threadIdx.x & 63) == 0)
        atomicMax((int*)MX, __float_as_int(m));
}

// ---------------- K4: messages + rowsum (atomic scatter) ----------------
__global__ __launch_bounds__(256) void k_msg(const int* __restrict__ edge,
                                             const float* __restrict__ S,
                                             const float* __restrict__ T,
                                             const float* __restrict__ H,
                                             const float* __restrict__ MX,
                                             float* __restrict__ ACC,
                                             float* __restrict__ RS) {
    const int lane = threadIdx.x & 63;
    const int e = blockIdx.x * 4 + (threadIdx.x >> 6);
    if (e >= NE) return;
    const float M = *MX;
    const int src = edge[e];
    const int dst = edge[NE + e];
    float v = S[src] + T[dst];
    float a = v >= 0.f ? v : ALPHA * v;
    float ev = expf(a - M);
    float hv = H[(size_t)dst * DDIM + lane];
    atomicAdd(&ACC[(size_t)src * DDIM + lane], ev * hv);
    if (lane == 0) atomicAdd(&RS[src], ev);
}

// ---------------- K5: out = acc / (rowsum + eps)  (fp32 output) ----------------
__global__ __launch_bounds__(256) void k_final(const float* __restrict__ ACC,
                                               const float* __restrict__ RS,
                                               float* __restrict__ out) {
    int i = blockIdx.x * 256 + threadIdx.x;
    if (i >= NN * DDIM) return;
    float r = RS[i >> 6];
    out[i] = ACC[i] / (r + EPSV);
}

extern "C" void kernel_launch(void* const* d_in, const int* in_sizes, int n_in,
                              void* d_out, int out_size, void* d_ws, size_t ws_size,
                              hipStream_t stream) {
    const float* X    = (const float*)d_in[0];
    const int*   edge = (const int*)d_in[1];
    const float* W    = (const float*)d_in[2];
    const float* attn = (const float*)d_in[3];

    float* ws  = (float*)d_ws;
    float* ACC = ws + OFF_ACC;
    float* RS  = ws + OFF_ROWSUM;
    float* MX  = ws + OFF_MAX;
    float* H   = ws + OFF_H;
    float* S   = ws + OFF_S;
    float* T   = ws + OFF_T;

    // zero acc + rowsum + max scratch (workspace is poisoned before each call)
    hipMemsetAsync(d_ws, 0, (size_t)OFF_H * sizeof(float), stream);

    k_gemm<<<256, 256, 0, stream>>>(X, W, H);
    k_st<<<200, 256, 0, stream>>>(H, attn, S, T);
    k_max<<<512, 256, 0, stream>>>(edge, S, T, MX);
    k_msg<<<NE / 4, 256, 0, stream>>>(edge, S, T, H, MX, ACC, RS);
    k_final<<<(NN * DDIM + 255) / 256, 256, 0, stream>>>(ACC, RS, (float*)d_out);
}

// Round 4
// 293.682 us; speedup vs baseline: 1.2202x; 1.2202x over previous
//
#include <hip/hip_runtime.h>
#include <stdint.h>

#define NN 50000
#define NE 800000
#define KDIM 256
#define DDIM 64
#define ALPHA 0.2f
#define EPSV 9e-15f
#define NB 196  // ceil(NN/256)

// d_ws layout in 4-byte units:
#define O_DEG   0         // 50000 int (zeroed)
#define O_MX    50000     // 16 (zeroed; [0] = global max as int-bits)
#define O_RP0   50016     // 50000 int  chunk-local exclusive scan
#define O_BSUM  100016    // 256 int    per-block sums
#define O_BOFF  100272    // 256 int    exclusive scan of block sums
#define O_RPF   100528    // 50000 int  final rowptr (start)
#define O_CUR   150528    // 50000 int  scatter cursor (starts == RPF)
#define O_H     200528    // 3,200,000 float
#define O_S     3400528   // 50000 float
#define O_T     3450528   // 50000 float
#define O_EDST  3500528   // 800000 int
#define O_EEV   4300528   // 800000 float
// total 5,100,528 * 4B = 20.4 MB (< previously-proven ws capacity)

typedef __bf16 bf16x8 __attribute__((ext_vector_type(8)));
typedef float f32x4 __attribute__((ext_vector_type(4)));

__device__ __forceinline__ ushort f2bf(float f) {
    uint32_t u = __float_as_uint(f);
    return (ushort)((u + 0x7fffu + ((u >> 16) & 1u)) >> 16);  // RNE
}

// ---- K1: h = x @ W (bf16 MFMA, fp32 out) with fused s,t epilogue ----
__global__ __launch_bounds__(256) void k_gemm(const float* __restrict__ X,
                                              const float* __restrict__ W,
                                              const float* __restrict__ attn,
                                              float* __restrict__ H,
                                              float* __restrict__ S,
                                              float* __restrict__ T) {
    const int lane = threadIdx.x & 63;
    const int wave = blockIdx.x * 4 + (threadIdx.x >> 6);
    const int nwaves = gridDim.x * 4;
    const int quad = lane >> 4;   // 0..3
    const int nn = lane & 15;     // 0..15

    // B fragments: B[k][n], k = s*32 + quad*8 + j, n = t*16 + nn
    bf16x8 bfrag[4][8];
#pragma unroll
    for (int t = 0; t < 4; ++t) {
#pragma unroll
        for (int s = 0; s < 8; ++s) {
            union { ushort u[8]; bf16x8 v; } bb;
#pragma unroll
            for (int j = 0; j < 8; ++j) {
                int k = s * 32 + quad * 8 + j;
                bb.u[j] = f2bf(W[k * DDIM + t * 16 + nn]);
            }
            bfrag[t][s] = bb.v;
        }
    }
    // attn weights for this lane's columns (col = t*16 + nn)
    float asrc[4], adst[4];
#pragma unroll
    for (int t = 0; t < 4; ++t) {
        asrc[t] = attn[t * 16 + nn];
        adst[t] = attn[DDIM + t * 16 + nn];
    }

    const int MT = NN / 16;  // 3125 exactly
    for (int mt = wave; mt < MT; mt += nwaves) {
        const int row0 = mt * 16;
        const float* xr = X + (size_t)(row0 + nn) * KDIM + quad * 8;
        bf16x8 afrag[8];
#pragma unroll
        for (int s = 0; s < 8; ++s) {
            float4 lo = *reinterpret_cast<const float4*>(xr + s * 32);
            float4 hi = *reinterpret_cast<const float4*>(xr + s * 32 + 4);
            union { ushort u[8]; bf16x8 v; } aa;
            aa.u[0] = f2bf(lo.x); aa.u[1] = f2bf(lo.y);
            aa.u[2] = f2bf(lo.z); aa.u[3] = f2bf(lo.w);
            aa.u[4] = f2bf(hi.x); aa.u[5] = f2bf(hi.y);
            aa.u[6] = f2bf(hi.z); aa.u[7] = f2bf(hi.w);
            afrag[s] = aa.v;
        }

        f32x4 acc[4];
#pragma unroll
        for (int t = 0; t < 4; ++t) acc[t] = {0.f, 0.f, 0.f, 0.f};
#pragma unroll
        for (int s = 0; s < 8; ++s)
#pragma unroll
            for (int t = 0; t < 4; ++t)
                acc[t] = __builtin_amdgcn_mfma_f32_16x16x32_bf16(
                    afrag[s], bfrag[t][s], acc[t], 0, 0, 0);

        // D: row = quad*4 + r, col = t*16 + nn
#pragma unroll
        for (int t = 0; t < 4; ++t)
#pragma unroll
            for (int r = 0; r < 4; ++r)
                H[(size_t)(row0 + quad * 4 + r) * DDIM + t * 16 + nn] = acc[t][r];

        // fused s,t: reduce acc over columns (16 lanes sharing a quad)
        float sp[4], tp[4];
#pragma unroll
        for (int r = 0; r < 4; ++r) { sp[r] = 0.f; tp[r] = 0.f; }
#pragma unroll
        for (int t = 0; t < 4; ++t)
#pragma unroll
            for (int r = 0; r < 4; ++r) {
                sp[r] = fmaf(acc[t][r], asrc[t], sp[r]);
                tp[r] = fmaf(acc[t][r], adst[t], tp[r]);
            }
#pragma unroll
        for (int m = 1; m < 16; m <<= 1)
#pragma unroll
            for (int r = 0; r < 4; ++r) {
                sp[r] += __shfl_xor(sp[r], m, 64);
                tp[r] += __shfl_xor(tp[r], m, 64);
            }
        if (nn == 0) {
#pragma unroll
            for (int r = 0; r < 4; ++r) {
                S[row0 + quad * 4 + r] = sp[r];
                T[row0 + quad * 4 + r] = tp[r];
            }
        }
    }
}

// ---- K2: degree count + global max of leaky-relu logits ----
__global__ __launch_bounds__(256) void k_maxdeg(const int* __restrict__ edge,
                                                const float* __restrict__ S,
                                                const float* __restrict__ T,
                                                int* __restrict__ DEG,
                                                int* __restrict__ MX) {
    float m = 0.0f;  // true max certainly > 0; int-compare valid for >= 0
    for (int e = blockIdx.x * 256 + threadIdx.x; e < NE; e += gridDim.x * 256) {
        int src = edge[e];
        int dst = edge[NE + e];
        atomicAdd(&DEG[src], 1);
        float v = S[src] + T[dst];
        float a = v >= 0.f ? v : ALPHA * v;
        m = fmaxf(m, a);
    }
#pragma unroll
    for (int off = 32; off > 0; off >>= 1)
        m = fmaxf(m, __shfl_down(m, off, 64));
    if ((threadIdx.x & 63) == 0) atomicMax(MX, __float_as_int(m));
}

// ---- block-inclusive-scan helper (256 threads) ----
__device__ __forceinline__ int block_incl_scan(int d, int* wsum) {
    const int lane = threadIdx.x & 63;
    const int wv = threadIdx.x >> 6;
    int v = d;
#pragma unroll
    for (int off = 1; off < 64; off <<= 1) {
        int u = __shfl_up(v, off, 64);
        if (lane >= off) v += u;
    }
    if (lane == 63) wsum[wv] = v;
    __syncthreads();
    int woff = 0;
#pragma unroll
    for (int w = 0; w < 4; ++w)
        if (w < wv) woff += wsum[w];
    return v + woff;
}

// ---- K3a: per-chunk exclusive scan of DEG ----
__global__ __launch_bounds__(256) void k_scanA(const int* __restrict__ DEG,
                                               int* __restrict__ RP0,
                                               int* __restrict__ BSUM) {
    __shared__ int wsum[4];
    int i = blockIdx.x * 256 + threadIdx.x;
    int d = (i < NN) ? DEG[i] : 0;
    int incl = block_incl_scan(d, wsum);
    if (i < NN) RP0[i] = incl - d;
    if (threadIdx.x == 255) BSUM[blockIdx.x] = incl;
}

// ---- K3b: exclusive scan of block sums (single block) ----
__global__ __launch_bounds__(256) void k_scanB(const int* __restrict__ BSUM,
                                               int* __restrict__ BOFF) {
    __shared__ int wsum[4];
    int d = (threadIdx.x < NB) ? BSUM[threadIdx.x] : 0;
    int incl = block_incl_scan(d, wsum);
    if (threadIdx.x < NB) BOFF[threadIdx.x] = incl - d;
}

// ---- K3c: final rowptr + cursor init ----
__global__ __launch_bounds__(256) void k_scanC(const int* __restrict__ RP0,
                                               const int* __restrict__ BOFF,
                                               int* __restrict__ RPF,
                                               int* __restrict__ CUR) {
    int i = blockIdx.x * 256 + threadIdx.x;
    if (i < NN) {
        int r = RP0[i] + BOFF[i >> 8];
        RPF[i] = r;
        CUR[i] = r;
    }
}

// ---- K4: scatter edges into CSR buckets with precomputed exp weights ----
__global__ __launch_bounds__(256) void k_scatter(const int* __restrict__ edge,
                                                 const float* __restrict__ S,
                                                 const float* __restrict__ T,
                                                 const int* __restrict__ MX,
                                                 int* __restrict__ CUR,
                                                 int* __restrict__ EDST,
                                                 float* __restrict__ EEV) {
    int e = blockIdx.x * 256 + threadIdx.x;
    if (e >= NE) return;
    const float M = __int_as_float(*MX);
    int src = edge[e];
    int dst = edge[NE + e];
    float v = S[src] + T[dst];
    float a = v >= 0.f ? v : ALPHA * v;
    float ev = __expf(a - M) == __expf(a - M) ? expf(a - M) : expf(a - M);
    int pos = atomicAdd(&CUR[src], 1);
    EDST[pos] = dst;
    EEV[pos] = ev;
}

// ---- K5: per-node gather-aggregate, direct output ----
__global__ __launch_bounds__(256) void k_agg(const int* __restrict__ RPF,
                                             const int* __restrict__ DEG,
                                             const int* __restrict__ EDST,
                                             const float* __restrict__ EEV,
                                             const float* __restrict__ H,
                                             float* __restrict__ out) {
    const int lane = threadIdx.x & 63;
    const int i = blockIdx.x * 4 + (threadIdx.x >> 6);
    if (i >= NN) return;
    const int start = RPF[i];
    const int deg = DEG[i];
    float acc = 0.f, rs = 0.f;
    for (int e = start; e < start + deg; ++e) {
        int dst = __builtin_amdgcn_readfirstlane(EDST[e]);
        float ev = EEV[e];
        acc = fmaf(ev, H[(size_t)dst * DDIM + lane], acc);
        rs += ev;
    }
    out[(size_t)i * DDIM + lane] = acc / (rs + EPSV);
}

extern "C" void kernel_launch(void* const* d_in, const int* in_sizes, int n_in,
                              void* d_out, int out_size, void* d_ws, size_t ws_size,
                              hipStream_t stream) {
    const float* X    = (const float*)d_in[0];
    const int*   edge = (const int*)d_in[1];
    const float* W    = (const float*)d_in[2];
    const float* attn = (const float*)d_in[3];

    int*   wi = (int*)d_ws;
    float* wf = (float*)d_ws;
    int*   DEG  = wi + O_DEG;
    int*   MX   = wi + O_MX;
    int*   RP0  = wi + O_RP0;
    int*   BSUM = wi + O_BSUM;
    int*   BOFF = wi + O_BOFF;
    int*   RPF  = wi + O_RPF;
    int*   CUR  = wi + O_CUR;
    float* H    = wf + O_H;
    float* S    = wf + O_S;
    float* T    = wf + O_T;
    int*   EDST = wi + O_EDST;
    float* EEV  = wf + O_EEV;

    // zero DEG + MX only (200 KB)
    hipMemsetAsync(d_ws, 0, (size_t)(O_RP0) * sizeof(int), stream);

    k_gemm<<<256, 256, 0, stream>>>(X, W, attn, H, S, T);
    k_maxdeg<<<512, 256, 0, stream>>>(edge, S, T, DEG, MX);
    k_scanA<<<NB, 256, 0, stream>>>(DEG, RP0, BSUM);
    k_scanB<<<1, 256, 0, stream>>>(BSUM, BOFF);
    k_scanC<<<NB, 256, 0, stream>>>(RP0, BOFF, RPF, CUR);
    k_scatter<<<NE / 256, 256, 0, stream>>>(edge, S, T, MX, CUR, EDST, EEV);
    k_agg<<<NN / 4, 256, 0, stream>>>(RPF, DEG, EDST, EEV, H, (float*)d_out);
}